// Round 1
// baseline (794.061 us; speedup 1.0000x reference)
//
#include <hip/hip_runtime.h>

typedef unsigned short u16;
typedef __attribute__((ext_vector_type(8))) short short8;
typedef __attribute__((ext_vector_type(4))) float f32x4;
typedef __attribute__((ext_vector_type(4))) unsigned short us4;

__device__ __forceinline__ u16 f2bf(float f) {
    unsigned u = __float_as_uint(f);
    u += 0x7fffu + ((u >> 16) & 1u);   // round-to-nearest-even
    return (u16)(u >> 16);
}
__device__ __forceinline__ float bf2f(u16 h) {
    return __uint_as_float(((unsigned)h) << 16);
}

// ---------------- X f32 -> bf16 (4 elems/thread) ----------------
__global__ __launch_bounds__(256) void k_cvt(const float* __restrict__ in,
                                             u16* __restrict__ out, long n) {
    long i = ((long)blockIdx.x * 256 + threadIdx.x) * 4;
    if (i >= n) return;
    float4 v = *(const float4*)(in + i);
    us4 o;
    o.x = f2bf(v.x); o.y = f2bf(v.y); o.z = f2bf(v.z); o.w = f2bf(v.w);
    *(us4*)(out + i) = o;
}

// ---------------- W (K,N) f32 -> Wt (N,K) bf16, with block-tri mask ----------------
// mask: zero where blk(k) > blk(n)  (64-blocks)
__global__ __launch_bounds__(256) void k_transpose(const float* __restrict__ W,
                                                   u16* __restrict__ Wt,
                                                   int K, int N, int mask) {
    __shared__ float tile[32][33];
    const int n0 = blockIdx.x * 32, k0 = blockIdx.y * 32;
    const int tx = threadIdx.x, ty = threadIdx.y;
#pragma unroll
    for (int j = 0; j < 32; j += 8)
        tile[ty + j][tx] = W[(size_t)(k0 + ty + j) * N + (n0 + tx)];
    __syncthreads();
#pragma unroll
    for (int j = 0; j < 32; j += 8) {
        int n = n0 + ty + j, k = k0 + tx;
        float v = tile[tx][ty + j];
        if (mask && ((k >> 6) > (n >> 6))) v = 0.0f;
        Wt[(size_t)n * K + k] = f2bf(v);
    }
}

// ---------------- extract W3[:, N-1] ----------------
__global__ __launch_bounds__(256) void k_extract(const float* __restrict__ W3,
                                                 float* __restrict__ col, int N) {
    int k = blockIdx.x * 256 + threadIdx.x;
    col[k] = W3[(size_t)k * N + (N - 1)];
}

// ---------------- bf16 GEMM: C = relu(A @ Bt^T + bias) -> bf16 ----------------
// A: M x K row-major bf16; Bt: N x K row-major bf16 (i.e. B transposed)
// m97 structure: 128x128 tile, 4 waves (64x64 each), BK=32, global_load_lds w=16
#define BM 128
#define BN 128
#define BK 32

__global__ __launch_bounds__(256) void k_gemm(const u16* __restrict__ A,
                                              const u16* __restrict__ Bt,
                                              const float* __restrict__ bias,
                                              u16* __restrict__ C,
                                              int M, int N, int K, int varK) {
    __shared__ u16 As[BM * BK];   // [m][k], row stride 32 elems (64 B)
    __shared__ u16 Bs[BN * BK];   // [n][k]
    const int bx = blockIdx.x, by = blockIdx.y;
    const int tid = (int)threadIdx.x;
    const int lane = tid & 63, wv = tid >> 6;
    const int wr = wv >> 1, wc = wv & 1;
    const int keff = varK ? min(K, (bx + 1) * BN) : K;

    const u16* Ab = A + (size_t)by * BM * K;
    const u16* Bb = Bt + (size_t)bx * BN * K;

    const int srow = tid >> 2;        // 0..63
    const int scol = (tid & 3) * 8;   // 0,8,16,24

    f32x4 acc[4][4];
#pragma unroll
    for (int i = 0; i < 4; ++i)
#pragma unroll
        for (int j = 0; j < 4; ++j)
            acc[i][j] = (f32x4){0.f, 0.f, 0.f, 0.f};

    const int l15 = lane & 15, lk = (lane >> 4) * 8;

    for (int kt = 0; kt < keff; kt += BK) {
        // stage A, B tiles: 2 x 1024B chunks each per wave-set
#pragma unroll
        for (int h = 0; h < 2; ++h) {
            __builtin_amdgcn_global_load_lds(
                (const __attribute__((address_space(1))) void*)(Ab + (size_t)(h * 64 + srow) * K + kt + scol),
                (__attribute__((address_space(3))) void*)(As + h * 2048 + wv * 512),
                16, 0, 0);
            __builtin_amdgcn_global_load_lds(
                (const __attribute__((address_space(1))) void*)(Bb + (size_t)(h * 64 + srow) * K + kt + scol),
                (__attribute__((address_space(3))) void*)(Bs + h * 2048 + wv * 512),
                16, 0, 0);
        }
        __syncthreads();   // compiler drains vmcnt before s_barrier

        short8 af[4], bfv[4];
#pragma unroll
        for (int mf = 0; mf < 4; ++mf)
            af[mf] = *(const short8*)(As + (wr * 64 + mf * 16 + l15) * BK + lk);
#pragma unroll
        for (int nf = 0; nf < 4; ++nf)
            bfv[nf] = *(const short8*)(Bs + (wc * 64 + nf * 16 + l15) * BK + lk);
#pragma unroll
        for (int mf = 0; mf < 4; ++mf)
#pragma unroll
            for (int nf = 0; nf < 4; ++nf)
                acc[mf][nf] = __builtin_amdgcn_mfma_f32_16x16x32_bf16(af[mf], bfv[nf], acc[mf][nf], 0, 0, 0);
        __syncthreads();   // protect LDS before next stage
    }

    // epilogue: bias + relu + bf16 store
    const int rbase = by * BM + wr * 64 + (lane >> 4) * 4;
    const int cbase = bx * BN + wc * 64 + l15;
#pragma unroll
    for (int nf = 0; nf < 4; ++nf) {
        const int gc = cbase + nf * 16;
        const float bv = bias[gc];
#pragma unroll
        for (int mf = 0; mf < 4; ++mf) {
#pragma unroll
            for (int r = 0; r < 4; ++r) {
                int gr = rbase + mf * 16 + r;
                float h = acc[mf][nf][r] + bv;
                h = fmaxf(h, 0.0f);
                C[(size_t)gr * N + gc] = f2bf(h);
            }
        }
    }
}

// ---------------- final matvec: out[m] = act[m,:] . col + b3[K-1] ----------------
__global__ __launch_bounds__(256) void k_matvec(const u16* __restrict__ act,
                                                const float* __restrict__ col,
                                                const float* __restrict__ b3,
                                                float* __restrict__ out, int K) {
    const int m = blockIdx.x, t = (int)threadIdx.x;
    const u16* row = act + (size_t)m * K;
    float acc = 0.f;
#pragma unroll
    for (int j = 0; j < 2; ++j) {
        int base = t * 16 + j * 8;
        short8 v = *(const short8*)(row + base);
#pragma unroll
        for (int u = 0; u < 8; ++u)
            acc += bf2f((u16)v[u]) * col[base + u];
    }
#pragma unroll
    for (int off = 32; off > 0; off >>= 1)
        acc += __shfl_down(acc, off);
    __shared__ float red[4];
    if ((t & 63) == 0) red[t >> 6] = acc;
    __syncthreads();
    if (t == 0) out[m] = red[0] + red[1] + red[2] + red[3] + b3[K - 1];
}

extern "C" void kernel_launch(void* const* d_in, const int* in_sizes, int n_in,
                              void* d_out, int out_size, void* d_ws, size_t ws_size,
                              hipStream_t stream) {
    const float* X  = (const float*)d_in[0];
    const float* W0 = (const float*)d_in[1];
    const float* b0 = (const float*)d_in[2];
    const float* W1 = (const float*)d_in[3];
    const float* b1 = (const float*)d_in[4];
    const float* W2 = (const float*)d_in[5];
    const float* b2 = (const float*)d_in[6];
    const float* W3 = (const float*)d_in[7];
    const float* b3 = (const float*)d_in[8];
    float* out = (float*)d_out;

    const int M = 8192, K0 = 1024, H = 4096;

    char* ws = (char*)d_ws;
    u16* Wt    = (u16*)(ws);                               // 33.5 MB (reused W0t/W1t/W2t)
    u16* actA  = (u16*)(ws + 33554432);                    // 67.1 MB
    u16* actB  = (u16*)(ws + 33554432 + 67108864);         // 67.1 MB
    u16* Xb    = actB;                                     // alias: dead before actB written
    float* col = (float*)(ws + 33554432 + 2 * 67108864);   // 16 KB

    // 1. X -> bf16
    k_cvt<<<dim3((M * K0) / 1024), 256, 0, stream>>>(X, Xb, (long)M * K0);
    // 2. W0^T (no mask)
    k_transpose<<<dim3(H / 32, K0 / 32), dim3(32, 8), 0, stream>>>(W0, Wt, K0, H, 0);
    // 3. h0 = relu(X @ W0 + b0)
    k_gemm<<<dim3(H / BN, M / BM), 256, 0, stream>>>(Xb, Wt, b0, actA, M, H, K0, 0);
    // 4. W1^T masked
    k_transpose<<<dim3(H / 32, H / 32), dim3(32, 8), 0, stream>>>(W1, Wt, H, H, 1);
    // 5. h1 = relu(h0 @ W1eff + b1)   (variable-K per column tile)
    k_gemm<<<dim3(H / BN, M / BM), 256, 0, stream>>>(actA, Wt, b1, actB, M, H, H, 1);
    // 6. W2^T masked
    k_transpose<<<dim3(H / 32, H / 32), dim3(32, 8), 0, stream>>>(W2, Wt, H, H, 1);
    // 7. h2 = relu(h1 @ W2eff + b2)
    k_gemm<<<dim3(H / BN, M / BM), 256, 0, stream>>>(actB, Wt, b2, actA, M, H, H, 1);
    // 8. W3 column 4095
    k_extract<<<dim3(H / 256), 256, 0, stream>>>(W3, col, H);
    // 9. out = h2 @ w3col + b3[4095]
    k_matvec<<<dim3(M), 256, 0, stream>>>(actA, col, b3, out, H);
}

// Round 2
// 512.749 us; speedup vs baseline: 1.5486x; 1.5486x over previous
//
#include <hip/hip_runtime.h>

typedef unsigned short u16;
typedef __attribute__((ext_vector_type(8))) short short8;
typedef __attribute__((ext_vector_type(4))) float f32x4;
typedef __attribute__((ext_vector_type(4))) unsigned short us4;

__device__ __forceinline__ u16 f2bf(float f) {
    unsigned u = __float_as_uint(f);
    u += 0x7fffu + ((u >> 16) & 1u);   // round-to-nearest-even
    return (u16)(u >> 16);
}
__device__ __forceinline__ float bf2f(u16 h) {
    return __uint_as_float(((unsigned)h) << 16);
}

// ---------------- X f32 -> bf16 (4 elems/thread) ----------------
__global__ __launch_bounds__(256) void k_cvt(const float* __restrict__ in,
                                             u16* __restrict__ out, long n) {
    long i = ((long)blockIdx.x * 256 + threadIdx.x) * 4;
    if (i >= n) return;
    float4 v = *(const float4*)(in + i);
    us4 o;
    o.x = f2bf(v.x); o.y = f2bf(v.y); o.z = f2bf(v.z); o.w = f2bf(v.w);
    *(us4*)(out + i) = o;
}

// ---------------- W (K,N) f32 -> Wt (N,K) bf16, block-tri mask ----------------
// 64-block mask is uniform over every 32x32 tile: skip reads of masked tiles.
__global__ __launch_bounds__(256) void k_transpose(const float* __restrict__ W,
                                                   u16* __restrict__ Wt,
                                                   int K, int N, int mask) {
    __shared__ float tile[32][33];
    const int n0 = blockIdx.x * 32, k0 = blockIdx.y * 32;
    const int tx = threadIdx.x, ty = threadIdx.y;
    if (mask && ((k0 >> 6) > (n0 >> 6))) {
#pragma unroll
        for (int j = 0; j < 32; j += 8)
            Wt[(size_t)(n0 + ty + j) * K + (k0 + tx)] = 0;
        return;
    }
#pragma unroll
    for (int j = 0; j < 32; j += 8)
        tile[ty + j][tx] = W[(size_t)(k0 + ty + j) * N + (n0 + tx)];
    __syncthreads();
#pragma unroll
    for (int j = 0; j < 32; j += 8)
        Wt[(size_t)(n0 + ty + j) * K + (k0 + tx)] = f2bf(tile[tx][ty + j]);
}

// ---------------- extract W3[:, N-1] ----------------
__global__ __launch_bounds__(256) void k_extract(const float* __restrict__ W3,
                                                 float* __restrict__ col, int N) {
    int k = blockIdx.x * 256 + threadIdx.x;
    col[k] = W3[(size_t)k * N + (N - 1)];
}

// ---------------- bf16 GEMM: C = relu(A @ Bt^T + bias) -> bf16 ----------------
// 256x256 tile, BK=32, 512 threads (8 waves 2x4), triple-buffered LDS,
// counted vmcnt (never 0 in main loop), XOR-swizzled LDS, XCD swizzle.
#define BM 256
#define BN 256
#define BK 32
#define BUFE 16384                     // elems per buffer: A 8192 | B 8192
#define GLDS(src, dst)                                                          \
    __builtin_amdgcn_global_load_lds(                                           \
        (const __attribute__((address_space(1))) void*)(src),                   \
        (__attribute__((address_space(3))) void*)(dst), 16, 0, 0)

__global__ __launch_bounds__(512, 2) void k_gemm(const u16* __restrict__ A,
                                                 const u16* __restrict__ Bt,
                                                 const float* __restrict__ bias,
                                                 u16* __restrict__ C,
                                                 int M, int N, int K, int varK) {
    __shared__ __align__(16) u16 lds[3 * BUFE];   // 96 KiB

    // bijective XCD swizzle (nwg = 512, divisible by 8)
    const int nwg = gridDim.x * gridDim.y;
    const int wg = blockIdx.y * gridDim.x + blockIdx.x;
    const int cpx = nwg >> 3;
    const int swz = (wg & 7) * cpx + (wg >> 3);
    const int bx = swz % gridDim.x, by = swz / gridDim.x;

    const int tid = (int)threadIdx.x;
    const int lane = tid & 63, wv = tid >> 6;
    const int wm = wv >> 2, wn = wv & 3;          // wave tile: 128(m) x 64(n)
    const int keff = varK ? min(K, (bx + 1) * BN) : K;
    const int nt = keff >> 5;                     // K-tiles of 32

    const u16* Ab = A + (size_t)by * BM * K;
    const u16* Bb = Bt + (size_t)bx * BN * K;

    // staging: 1024 chunks of 16B per matrix per tile; thread t owns chunks t, t+512.
    // LDS dest linear (chunk c -> elem c*8); global source pre-swizzled:
    // row = c>>2, logical slot = (c&3) ^ ((c>>3)&3)   [involution with read side]
    const int c0 = tid, c1 = tid + 512;
    const int ar0 = c0 >> 2, as0 = ((c0 & 3) ^ ((c0 >> 3) & 3)) * 8;
    const int ar1 = c1 >> 2, as1 = ((c1 & 3) ^ ((c1 >> 3) & 3)) * 8;
    const u16* pA0 = Ab + (size_t)ar0 * K + as0;
    const u16* pA1 = Ab + (size_t)ar1 * K + as1;
    const u16* pB0 = Bb + (size_t)ar0 * K + as0;
    const u16* pB1 = Bb + (size_t)ar1 * K + as1;
    u16* dA0 = lds + c0 * 8;
    u16* dA1 = lds + c1 * 8;
    u16* dB0 = lds + 8192 + c0 * 8;
    u16* dB1 = lds + 8192 + c1 * 8;

    // fragment read offsets (swizzled slot: (lane>>4) ^ ((row>>1)&3), row%16 = l15)
    const int l15 = lane & 15;
    const int sl8 = (((lane >> 4) ^ ((l15 >> 1) & 3))) * 8;
    const int aoff = (wm * 128 + l15) * BK + sl8;
    const int boff = 8192 + (wn * 64 + l15) * BK + sl8;

    f32x4 acc[8][4];
#pragma unroll
    for (int i = 0; i < 8; ++i)
#pragma unroll
        for (int j = 0; j < 4; ++j)
            acc[i][j] = (f32x4){0.f, 0.f, 0.f, 0.f};

    // prologue: stage tiles 0,1; guarantee tile 0 landed (all waves) then barrier
    GLDS(pA0, dA0); GLDS(pA1, dA1); GLDS(pB0, dB0); GLDS(pB1, dB1);
    if (nt > 1) {
        GLDS(pA0 + BK, dA0 + BUFE); GLDS(pA1 + BK, dA1 + BUFE);
        GLDS(pB0 + BK, dB0 + BUFE); GLDS(pB1 + BK, dB1 + BUFE);
        asm volatile("s_waitcnt vmcnt(4)\n\ts_barrier" ::: "memory");
    } else {
        asm volatile("s_waitcnt vmcnt(0)\n\ts_barrier" ::: "memory");
    }
    pA0 += 2 * BK; pA1 += 2 * BK; pB0 += 2 * BK; pB1 += 2 * BK;

    int bo = 0;            // LDS buffer offset of tile t
    int bs = 2 * BUFE;     // LDS buffer offset of tile t+2
    for (int t = 0; t < nt; ++t) {
        if (t + 2 < nt) {  // stage tile t+2 (buffer last read at t-1: WAR-safe)
            GLDS(pA0, dA0 + bs); GLDS(pA1, dA1 + bs);
            GLDS(pB0, dB0 + bs); GLDS(pB1, dB1 + bs);
        }
        pA0 += BK; pA1 += BK; pB0 += BK; pB1 += BK;

        short8 af[8], bfv[4];
#pragma unroll
        for (int mf = 0; mf < 8; ++mf)
            af[mf] = *(const short8*)(lds + bo + aoff + mf * 512);
#pragma unroll
        for (int nf = 0; nf < 4; ++nf)
            bfv[nf] = *(const short8*)(lds + bo + boff + nf * 512);

        __builtin_amdgcn_s_setprio(1);
#pragma unroll
        for (int mf = 0; mf < 8; ++mf)
#pragma unroll
            for (int nf = 0; nf < 4; ++nf)
                acc[mf][nf] = __builtin_amdgcn_mfma_f32_16x16x32_bf16(af[mf], bfv[nf], acc[mf][nf], 0, 0, 0);
        __builtin_amdgcn_s_setprio(0);

        if (t + 1 < nt) {
            if (t + 2 < nt)   // keep tile t+2's 4 loads in flight; tile t+1 landed
                asm volatile("s_waitcnt vmcnt(4)\n\ts_barrier" ::: "memory");
            else
                asm volatile("s_waitcnt vmcnt(0)\n\ts_barrier" ::: "memory");
        }
        bo += BUFE; if (bo == 3 * BUFE) bo = 0;
        bs += BUFE; if (bs == 3 * BUFE) bs = 0;
    }

    // epilogue: bias + relu + bf16 store
    const int rbase = by * BM + wm * 128 + (lane >> 4) * 4;
    const int cbase = bx * BN + wn * 64 + l15;
#pragma unroll
    for (int nf = 0; nf < 4; ++nf) {
        const int gc = cbase + nf * 16;
        const float bv = bias[gc];
#pragma unroll
        for (int mf = 0; mf < 8; ++mf) {
#pragma unroll
            for (int r = 0; r < 4; ++r) {
                int gr = rbase + mf * 16 + r;
                float h = acc[mf][nf][r] + bv;
                h = fmaxf(h, 0.0f);
                C[(size_t)gr * N + gc] = f2bf(h);
            }
        }
    }
}

// ---------------- final matvec: out[m] = act[m,:] . col + b3[K-1] ----------------
__global__ __launch_bounds__(256) void k_matvec(const u16* __restrict__ act,
                                                const float* __restrict__ col,
                                                const float* __restrict__ b3,
                                                float* __restrict__ out, int K) {
    const int m = blockIdx.x, t = (int)threadIdx.x;
    const u16* row = act + (size_t)m * K;
    float acc = 0.f;
#pragma unroll
    for (int j = 0; j < 2; ++j) {
        int base = t * 16 + j * 8;
        short8 v = *(const short8*)(row + base);
#pragma unroll
        for (int u = 0; u < 8; ++u)
            acc += bf2f((u16)v[u]) * col[base + u];
    }
#pragma unroll
    for (int off = 32; off > 0; off >>= 1)
        acc += __shfl_down(acc, off);
    __shared__ float red[4];
    if ((t & 63) == 0) red[t >> 6] = acc;
    __syncthreads();
    if (t == 0) out[m] = red[0] + red[1] + red[2] + red[3] + b3[K - 1];
}

extern "C" void kernel_launch(void* const* d_in, const int* in_sizes, int n_in,
                              void* d_out, int out_size, void* d_ws, size_t ws_size,
                              hipStream_t stream) {
    const float* X  = (const float*)d_in[0];
    const float* W0 = (const float*)d_in[1];
    const float* b0 = (const float*)d_in[2];
    const float* W1 = (const float*)d_in[3];
    const float* b1 = (const float*)d_in[4];
    const float* W2 = (const float*)d_in[5];
    const float* b2 = (const float*)d_in[6];
    const float* W3 = (const float*)d_in[7];
    const float* b3 = (const float*)d_in[8];
    float* out = (float*)d_out;

    const int M = 8192, K0 = 1024, H = 4096;

    char* ws = (char*)d_ws;
    u16* Wt    = (u16*)(ws);                               // 33.5 MB (reused)
    u16* actA  = (u16*)(ws + 33554432);                    // 67.1 MB
    u16* actB  = (u16*)(ws + 33554432 + 67108864);         // 67.1 MB
    u16* Xb    = actB;                                     // alias: dead before actB written
    float* col = (float*)(ws + 33554432 + 2 * 67108864);   // 16 KB

    // 1. X -> bf16
    k_cvt<<<dim3((M * K0) / 1024), 256, 0, stream>>>(X, Xb, (long)M * K0);
    // 2. W0^T (no mask)
    k_transpose<<<dim3(H / 32, K0 / 32), dim3(32, 8), 0, stream>>>(W0, Wt, K0, H, 0);
    // 3. h0 = relu(X @ W0 + b0)
    k_gemm<<<dim3(H / BN, M / BM), 512, 0, stream>>>(Xb, Wt, b0, actA, M, H, K0, 0);
    // 4. W1^T masked
    k_transpose<<<dim3(H / 32, H / 32), dim3(32, 8), 0, stream>>>(W1, Wt, H, H, 1);
    // 5. h1 = relu(h0 @ W1eff + b1)   (variable-K per column tile)
    k_gemm<<<dim3(H / BN, M / BM), 512, 0, stream>>>(actA, Wt, b1, actB, M, H, H, 1);
    // 6. W2^T masked
    k_transpose<<<dim3(H / 32, H / 32), dim3(32, 8), 0, stream>>>(W2, Wt, H, H, 1);
    // 7. h2 = relu(h1 @ W2eff + b2)
    k_gemm<<<dim3(H / BN, M / BM), 512, 0, stream>>>(actB, Wt, b2, actA, M, H, H, 1);
    // 8. W3 column 4095
    k_extract<<<dim3(H / 256), 256, 0, stream>>>(W3, col, H);
    // 9. out = h2 @ w3col + b3[4095]
    k_matvec<<<dim3(M), 256, 0, stream>>>(actA, col, b3, out, H);
}

// Round 3
// 413.009 us; speedup vs baseline: 1.9226x; 1.2415x over previous
//
#include <hip/hip_runtime.h>

typedef unsigned short u16;
typedef __attribute__((ext_vector_type(8))) short short8;
typedef __attribute__((ext_vector_type(4))) float f32x4;
typedef __attribute__((ext_vector_type(4))) unsigned short us4;

__device__ __forceinline__ u16 f2bf(float f) {
    unsigned u = __float_as_uint(f);
    u += 0x7fffu + ((u >> 16) & 1u);   // round-to-nearest-even
    return (u16)(u >> 16);
}
__device__ __forceinline__ float bf2f(u16 h) {
    return __uint_as_float(((unsigned)h) << 16);
}

// ---------------- X f32 -> bf16 (4 elems/thread) ----------------
__global__ __launch_bounds__(256) void k_cvt(const float* __restrict__ in,
                                             u16* __restrict__ out, long n) {
    long i = ((long)blockIdx.x * 256 + threadIdx.x) * 4;
    if (i >= n) return;
    float4 v = *(const float4*)(in + i);
    us4 o;
    o.x = f2bf(v.x); o.y = f2bf(v.y); o.z = f2bf(v.z); o.w = f2bf(v.w);
    *(us4*)(out + i) = o;
}

// ---------------- W (K,N) f32 -> Wt (N,K) bf16, block-tri mask ----------------
// 64-block mask uniform over 32x32 tiles: skip reads of masked tiles; skip
// writes of masked tiles beyond the consumer's keff = ((n0>>8)+1)*256.
__global__ __launch_bounds__(256) void k_transpose(const float* __restrict__ W,
                                                   u16* __restrict__ Wt,
                                                   int K, int N, int mask) {
    __shared__ float tile[32][33];
    const int n0 = blockIdx.x * 32, k0 = blockIdx.y * 32;
    const int tx = threadIdx.x, ty = threadIdx.y;
    if (mask && ((k0 >> 6) > (n0 >> 6))) {
        if (k0 >= ((n0 >> 8) + 1) * 256) return;   // never read by varK GEMM
#pragma unroll
        for (int j = 0; j < 32; j += 8)
            Wt[(size_t)(n0 + ty + j) * K + (k0 + tx)] = 0;
        return;
    }
#pragma unroll
    for (int j = 0; j < 32; j += 8)
        tile[ty + j][tx] = W[(size_t)(k0 + ty + j) * N + (n0 + tx)];
    __syncthreads();
#pragma unroll
    for (int j = 0; j < 32; j += 8)
        Wt[(size_t)(n0 + ty + j) * K + (k0 + tx)] = f2bf(tile[tx][ty + j]);
}

// ---------------- extract W3[:, N-1] ----------------
__global__ __launch_bounds__(256) void k_extract(const float* __restrict__ W3,
                                                 float* __restrict__ col, int N) {
    int k = blockIdx.x * 256 + threadIdx.x;
    col[k] = W3[(size_t)k * N + (N - 1)];
}

// ---------------- bf16 GEMM: C = relu(A @ Bt^T + bias) -> bf16 ----------------
// 256x256 tile, BK=32, 512 threads (8 waves 2x4), QUAD-buffered LDS (128 KiB),
// register-double-buffered fragments (ds_read t+1 overlaps MFMA t),
// counted vmcnt (never 0 mid-loop), XOR-swizzled LDS, LPT order for varK.
#define BM 256
#define BN 256
#define BK 32
#define BUFE 16384                     // elems per buffer: A 8192 | B 8192
#define GLDS(src, dst)                                                          \
    __builtin_amdgcn_global_load_lds(                                           \
        (const __attribute__((address_space(1))) void*)(src),                   \
        (__attribute__((address_space(3))) void*)(dst), 16, 0, 0)

__global__ __launch_bounds__(512, 2) void k_gemm(const u16* __restrict__ A,
                                                 const u16* __restrict__ Bt,
                                                 const float* __restrict__ bias,
                                                 u16* __restrict__ C,
                                                 int M, int N, int K, int varK) {
    __shared__ __align__(16) u16 lds[4 * BUFE];   // 128 KiB

    const int d = blockIdx.y * gridDim.x + blockIdx.x;   // dispatch-order index
    int bx, by;
    if (varK) {
        // LPT: heavy column-tiles (large bx -> large keff) dispatch first
        bx = (int)gridDim.x - 1 - (d / (int)gridDim.y);
        by = d % (int)gridDim.y;
    } else {
        // bijective XCD swizzle (nwg divisible by 8)
        const int nwg = (int)(gridDim.x * gridDim.y);
        const int cpx = nwg >> 3;
        const int swz = (d & 7) * cpx + (d >> 3);
        bx = swz % (int)gridDim.x;
        by = swz / (int)gridDim.x;
    }

    const int tid = (int)threadIdx.x;
    const int lane = tid & 63, wv = tid >> 6;
    const int wm = wv >> 2, wn = wv & 3;          // wave tile: 128(m) x 64(n)
    const int keff = varK ? min(K, (bx + 1) * BN) : K;
    const int nt = keff >> 5;                     // K-tiles of 32; always even, >=8

    const u16* Ab = A + (size_t)by * BM * K;
    const u16* Bb = Bt + (size_t)bx * BN * K;

    // staging: thread t owns 16B chunks t and t+512 of each matrix tile.
    // LDS dest linear; global source pre-swizzled (involution with read side):
    // row = c>>2, slot = (c&3) ^ ((c>>3)&3)
    const int c0 = tid, c1 = tid + 512;
    const int ar0 = c0 >> 2, as0 = ((c0 & 3) ^ ((c0 >> 3) & 3)) * 8;
    const int ar1 = c1 >> 2, as1 = ((c1 & 3) ^ ((c1 >> 3) & 3)) * 8;
    const u16* pA0 = Ab + (size_t)ar0 * K + as0;
    const u16* pA1 = Ab + (size_t)ar1 * K + as1;
    const u16* pB0 = Bb + (size_t)ar0 * K + as0;
    const u16* pB1 = Bb + (size_t)ar1 * K + as1;
    u16* dA0 = lds + c0 * 8;
    u16* dA1 = lds + c1 * 8;
    u16* dB0 = lds + 8192 + c0 * 8;
    u16* dB1 = lds + 8192 + c1 * 8;

    // fragment read offsets (swizzled slot: (lane>>4) ^ ((row>>1)&3))
    const int l15 = lane & 15;
    const int sl8 = (((lane >> 4) ^ ((l15 >> 1) & 3))) * 8;
    const int aoff = (wm * 128 + l15) * BK + sl8;
    const int boff = 8192 + (wn * 64 + l15) * BK + sl8;

#define STAGE(t)                                                      \
    {                                                                 \
        const size_t o = (size_t)(t)*BK;                              \
        const int b = ((t)&3) * BUFE;                                 \
        GLDS(pA0 + o, dA0 + b); GLDS(pA1 + o, dA1 + b);               \
        GLDS(pB0 + o, dB0 + b); GLDS(pB1 + o, dB1 + b);               \
    }
#define DSREAD(t, af, bf)                                             \
    {                                                                 \
        const int b = ((t)&3) * BUFE;                                 \
        _Pragma("unroll")                                             \
        for (int mf = 0; mf < 8; ++mf)                                \
            af[mf] = *(const short8*)(lds + b + aoff + mf * 512);     \
        _Pragma("unroll")                                             \
        for (int nf = 0; nf < 4; ++nf)                                \
            bf[nf] = *(const short8*)(lds + b + boff + nf * 512);     \
    }
#define MFMA_SET(af, bf)                                              \
    {                                                                 \
        __builtin_amdgcn_s_setprio(1);                                \
        _Pragma("unroll")                                             \
        for (int mf = 0; mf < 8; ++mf)                                \
            _Pragma("unroll")                                         \
            for (int nf = 0; nf < 4; ++nf)                            \
                acc[mf][nf] = __builtin_amdgcn_mfma_f32_16x16x32_bf16(\
                    af[mf], bf[nf], acc[mf][nf], 0, 0, 0);            \
        __builtin_amdgcn_s_setprio(0);                                \
    }
#define WAITBAR4  asm volatile("s_waitcnt vmcnt(4)\n\ts_barrier" ::: "memory")
#define WAITBAR0  asm volatile("s_waitcnt vmcnt(0)\n\ts_barrier" ::: "memory")

    f32x4 acc[8][4];
#pragma unroll
    for (int i = 0; i < 8; ++i)
#pragma unroll
        for (int j = 0; j < 4; ++j)
            acc[i][j] = (f32x4){0.f, 0.f, 0.f, 0.f};

    short8 afA[8], bfA[4], afB[8], bfB[4];

    // prologue: stage tiles 0,1,2; tiles 0,1 landed; read frags(0)
    STAGE(0); STAGE(1); STAGE(2);
    WAITBAR4;                 // 4 outstanding = stage(2); tiles 0,1 landed
    DSREAD(0, afA, bfA);

    // invariant at even-body t entry: tiles <= t+1 landed in LDS
    for (int t = 0; t < nt; t += 2) {
        // ---- even body: compute t (set A), read t+1 (set B) ----
        if (t + 3 < nt) STAGE(t + 3);
        DSREAD(t + 1, afB, bfB);
        MFMA_SET(afA, bfA);
        if (t + 3 < nt) WAITBAR4; else WAITBAR0;   // tile t+2 landed
        // ---- odd body u=t+1: compute u (set B), read u+1 (set A) ----
        const int u = t + 1;
        if (u + 3 < nt) STAGE(u + 3);
        if (u + 1 < nt) DSREAD(u + 1, afA, bfA);
        MFMA_SET(afB, bfB);
        if (u + 1 < nt) { if (u + 3 < nt) WAITBAR4; else WAITBAR0; }
    }

    // epilogue: bias + relu + bf16 store
    const int rbase = by * BM + wm * 128 + (lane >> 4) * 4;
    const int cbase = bx * BN + wn * 64 + l15;
#pragma unroll
    for (int nf = 0; nf < 4; ++nf) {
        const int gc = cbase + nf * 16;
        const float bv = bias[gc];
#pragma unroll
        for (int mf = 0; mf < 8; ++mf) {
#pragma unroll
            for (int r = 0; r < 4; ++r) {
                int gr = rbase + mf * 16 + r;
                float h = acc[mf][nf][r] + bv;
                h = fmaxf(h, 0.0f);
                C[(size_t)gr * N + gc] = f2bf(h);
            }
        }
    }
#undef STAGE
#undef DSREAD
#undef MFMA_SET
#undef WAITBAR4
#undef WAITBAR0
}

// ---------------- final matvec: out[m] = act[m,:] . col + b3[K-1] ----------------
__global__ __launch_bounds__(256) void k_matvec(const u16* __restrict__ act,
                                                const float* __restrict__ col,
                                                const float* __restrict__ b3,
                                                float* __restrict__ out, int K) {
    const int m = blockIdx.x, t = (int)threadIdx.x;
    const u16* row = act + (size_t)m * K;
    float acc = 0.f;
#pragma unroll
    for (int j = 0; j < 2; ++j) {
        int base = t * 16 + j * 8;
        short8 v = *(const short8*)(row + base);
#pragma unroll
        for (int u = 0; u < 8; ++u)
            acc += bf2f((u16)v[u]) * col[base + u];
    }
#pragma unroll
    for (int off = 32; off > 0; off >>= 1)
        acc += __shfl_down(acc, off);
    __shared__ float red[4];
    if ((t & 63) == 0) red[t >> 6] = acc;
    __syncthreads();
    if (t == 0) out[m] = red[0] + red[1] + red[2] + red[3] + b3[K - 1];
}

extern "C" void kernel_launch(void* const* d_in, const int* in_sizes, int n_in,
                              void* d_out, int out_size, void* d_ws, size_t ws_size,
                              hipStream_t stream) {
    const float* X  = (const float*)d_in[0];
    const float* W0 = (const float*)d_in[1];
    const float* b0 = (const float*)d_in[2];
    const float* W1 = (const float*)d_in[3];
    const float* b1 = (const float*)d_in[4];
    const float* W2 = (const float*)d_in[5];
    const float* b2 = (const float*)d_in[6];
    const float* W3 = (const float*)d_in[7];
    const float* b3 = (const float*)d_in[8];
    float* out = (float*)d_out;

    const int M = 8192, K0 = 1024, H = 4096;

    char* ws = (char*)d_ws;
    u16* Wt    = (u16*)(ws);                               // 33.5 MB (reused)
    u16* actA  = (u16*)(ws + 33554432);                    // 67.1 MB
    u16* actB  = (u16*)(ws + 33554432 + 67108864);         // 67.1 MB
    u16* Xb    = actB;                                     // alias: dead before actB written
    float* col = (float*)(ws + 33554432 + 2 * 67108864);   // 16 KB

    // 1. X -> bf16
    k_cvt<<<dim3((M * K0) / 1024), 256, 0, stream>>>(X, Xb, (long)M * K0);
    // 2. W0^T (no mask)
    k_transpose<<<dim3(H / 32, K0 / 32), dim3(32, 8), 0, stream>>>(W0, Wt, K0, H, 0);
    // 3. h0 = relu(X @ W0 + b0)
    k_gemm<<<dim3(H / BN, M / BM), 512, 0, stream>>>(Xb, Wt, b0, actA, M, H, K0, 0);
    // 4. W1^T masked
    k_transpose<<<dim3(H / 32, H / 32), dim3(32, 8), 0, stream>>>(W1, Wt, H, H, 1);
    // 5. h1 = relu(h0 @ W1eff + b1)   (variable-K per column tile, LPT order)
    k_gemm<<<dim3(H / BN, M / BM), 512, 0, stream>>>(actA, Wt, b1, actB, M, H, H, 1);
    // 6. W2^T masked
    k_transpose<<<dim3(H / 32, H / 32), dim3(32, 8), 0, stream>>>(W2, Wt, H, H, 1);
    // 7. h2 = relu(h1 @ W2eff + b2)
    k_gemm<<<dim3(H / BN, M / BM), 512, 0, stream>>>(actB, Wt, b2, actA, M, H, H, 1);
    // 8. W3 column 4095
    k_extract<<<dim3(H / 256), 256, 0, stream>>>(W3, col, H);
    // 9. out = h2 @ w3col + b3[4095]
    k_matvec<<<dim3(M), 256, 0, stream>>>(actA, col, b3, out, H);
}

// Round 4
// 387.367 us; speedup vs baseline: 2.0499x; 1.0662x over previous
//
#include <hip/hip_runtime.h>

typedef unsigned short u16;
typedef __attribute__((ext_vector_type(8))) short short8;
typedef __attribute__((ext_vector_type(4))) float f32x4;
typedef __attribute__((ext_vector_type(4))) unsigned short us4;

__device__ __forceinline__ u16 f2bf(float f) {
    unsigned u = __float_as_uint(f);
    u += 0x7fffu + ((u >> 16) & 1u);   // round-to-nearest-even
    return (u16)(u >> 16);
}
__device__ __forceinline__ float bf2f(u16 h) {
    return __uint_as_float(((unsigned)h) << 16);
}

// ---------------- X f32 -> bf16 (4 elems/thread) ----------------
__global__ __launch_bounds__(256) void k_cvt(const float* __restrict__ in,
                                             u16* __restrict__ out, long n) {
    long i = ((long)blockIdx.x * 256 + threadIdx.x) * 4;
    if (i >= n) return;
    float4 v = *(const float4*)(in + i);
    us4 o;
    o.x = f2bf(v.x); o.y = f2bf(v.y); o.z = f2bf(v.z); o.w = f2bf(v.w);
    *(us4*)(out + i) = o;
}

// ---------------- W (K,N) f32 -> Wt (N,K) bf16, block-tri mask ----------------
__global__ __launch_bounds__(256) void k_transpose(const float* __restrict__ W,
                                                   u16* __restrict__ Wt,
                                                   int K, int N, int mask) {
    __shared__ float tile[32][33];
    const int n0 = blockIdx.x * 32, k0 = blockIdx.y * 32;
    const int tx = threadIdx.x, ty = threadIdx.y;
    if (mask && ((k0 >> 6) > (n0 >> 6))) {
        if (k0 >= ((n0 >> 8) + 1) * 256) return;   // never read by varK GEMM
#pragma unroll
        for (int j = 0; j < 32; j += 8)
            Wt[(size_t)(n0 + ty + j) * K + (k0 + tx)] = 0;
        return;
    }
#pragma unroll
    for (int j = 0; j < 32; j += 8)
        tile[ty + j][tx] = W[(size_t)(k0 + ty + j) * N + (n0 + tx)];
    __syncthreads();
#pragma unroll
    for (int j = 0; j < 32; j += 8)
        Wt[(size_t)(n0 + ty + j) * K + (k0 + tx)] = f2bf(tile[tx][ty + j]);
}

// ---------------- extract W3[:, N-1] ----------------
__global__ __launch_bounds__(256) void k_extract(const float* __restrict__ W3,
                                                 float* __restrict__ col, int N) {
    int k = blockIdx.x * 256 + threadIdx.x;
    col[k] = W3[(size_t)k * N + (N - 1)];
}

// ---------------- bf16 GEMM: C = relu(A @ Bt^T + bias) -> bf16 ----------------
// 256x256 tile, BK=64, 512 threads (8 waves 2x4), 2 LDS buffers (128 KiB),
// 4 phases/K-tile: [ds_read next | stage 2 chunks | BAR | lgkm0 | 16 MFMA |
// vmcnt(2) BAR].  Counted vmcnt never drains mid-loop; vmcnt precedes the
// barrier so landing guarantees propagate cross-wave.  XOR-swizzle slot^=row&7
// on both stage-source and ds_read.  LPT order for varK; XCD swizzle else.
#define BM 256
#define BN 256
#define BK 64
#define GLDS(src, dst)                                                          \
    __builtin_amdgcn_global_load_lds(                                           \
        (const __attribute__((address_space(1))) void*)(src),                   \
        (__attribute__((address_space(3))) void*)(dst), 16, 0, 0)

__global__ __launch_bounds__(512, 2) void k_gemm(const u16* __restrict__ A,
                                                 const u16* __restrict__ Bt,
                                                 const float* __restrict__ bias,
                                                 u16* __restrict__ C,
                                                 int M, int N, int K, int varK) {
    __shared__ __align__(16) u16 lds[2 * 32768];   // 128 KiB: buf{0,1} x (A 16K | B 16K elems)

    const int d = blockIdx.y * gridDim.x + blockIdx.x;
    int bx, by;
    if (varK) {   // LPT: heavy column-tiles (large keff) first
        bx = (int)gridDim.x - 1 - (d / (int)gridDim.y);
        by = d % (int)gridDim.y;
    } else {      // bijective XCD swizzle (nwg divisible by 8)
        const int nwg = (int)(gridDim.x * gridDim.y);
        const int cpx = nwg >> 3;
        const int swz = (d & 7) * cpx + (d >> 3);
        bx = swz % (int)gridDim.x;
        by = swz / (int)gridDim.x;
    }

    const int tid = (int)threadIdx.x;
    const int lane = tid & 63, wv = tid >> 6;
    const int wm = wv >> 2, wn = wv & 3;          // wave tile: 128(m) x 64(n)
    const int keff = varK ? min(K, (bx + 1) * BN) : K;
    const int nt = keff >> 6;                     // K-tiles of 64; nt >= 4 always

    const u16* Ab = A + (size_t)by * BM * K;
    const u16* Bb = Bt + (size_t)bx * BN * K;

    // ---- staging addressing: chunk = 64 rows x 64 k = 8KB = 1 gload/thread ----
    // dest (linear): buf + [A0|B 16384] + ci*4096 + tid*8
    // source row = ci*64 + (tid>>3); source k-slot = (tid&7) ^ (row&7)  (pre-swizzle)
    const int tr = tid >> 3, ts = tid & 7;
    const int ss = ts ^ (tr & 7);
    const u16* aSrc = Ab + (size_t)tr * K + ss * 8;
    const u16* bSrc = Bb + (size_t)tr * K + ss * 8;

#define STA(tt, ci, dbuf) GLDS(aSrc + (size_t)(tt) * BK + (size_t)(ci) * 64 * K, \
                               lds + (dbuf) + (ci) * 4096 + tid * 8)
#define STB(tt, ci, dbuf) GLDS(bSrc + (size_t)(tt) * BK + (size_t)(ci) * 64 * K, \
                               lds + (dbuf) + 16384 + (ci) * 4096 + tid * 8)

    // ---- fragment read addressing (swizzled: lds slot = (ks*4+(lane>>4)) ^ (l15&7)) ----
    const int l15 = lane & 15;
    const int sw = (lane >> 4) ^ (l15 & 7);
    const int arow = wm * 128 + l15;
    const int brow = wn * 64 + l15;

#define RDA(dst, mfh, ks, dbuf)                                                        \
    {                                                                                  \
        _Pragma("unroll")                                                              \
        for (int i = 0; i < 4; ++i)                                                    \
            dst[i] = *(const short8*)(lds + (dbuf) + (arow + (mfh) * 64 + i * 16) * 64 \
                                      + ((sw ^ ((ks) << 2))) * 8);                     \
    }
#define RDB(dst, ks, dbuf)                                                             \
    {                                                                                  \
        _Pragma("unroll")                                                              \
        for (int nf = 0; nf < 4; ++nf)                                                 \
            dst[nf] = *(const short8*)(lds + (dbuf) + 16384 + (brow + nf * 16) * 64    \
                                       + ((sw ^ ((ks) << 2))) * 8);                    \
    }
#define MFMA16(afS, bfS, mb)                                                           \
    {                                                                                  \
        __builtin_amdgcn_s_setprio(1);                                                 \
        _Pragma("unroll")                                                              \
        for (int i = 0; i < 4; ++i)                                                    \
            _Pragma("unroll")                                                          \
            for (int nf = 0; nf < 4; ++nf)                                             \
                acc[(mb) + i][nf] = __builtin_amdgcn_mfma_f32_16x16x32_bf16(           \
                    afS[i], bfS[nf], acc[(mb) + i][nf], 0, 0, 0);                      \
        __builtin_amdgcn_s_setprio(0);                                                 \
    }
#define MIDSYNC                                                   \
    __builtin_amdgcn_s_barrier();                                 \
    asm volatile("s_waitcnt lgkmcnt(0)" ::: "memory");            \
    __builtin_amdgcn_sched_barrier(0);
#define ENDSYNC                                                   \
    asm volatile("s_waitcnt vmcnt(2)" ::: "memory");              \
    __builtin_amdgcn_s_barrier();

    f32x4 acc[8][4];
#pragma unroll
    for (int i = 0; i < 8; ++i)
#pragma unroll
        for (int j = 0; j < 4; ++j)
            acc[i][j] = (f32x4){0.f, 0.f, 0.f, 0.f};

    short8 afX[4], afY[4], bfA[4], bfB[4];

    // ---- prologue: stage t0 (8 chunks) then t1.b (4); t0 landed via vmcnt(4) ----
    STA(0, 0, 0); STA(0, 2, 0); STA(0, 1, 0); STA(0, 3, 0);
    STB(0, 0, 0); STB(0, 1, 0); STB(0, 2, 0); STB(0, 3, 0);
    STB(1, 0, 32768); STB(1, 1, 32768); STB(1, 2, 32768); STB(1, 3, 32768);
    asm volatile("s_waitcnt vmcnt(4)" ::: "memory");
    __builtin_amdgcn_s_barrier();
    RDA(afX, 0, 0, 0);
    RDB(bfA, 0, 0);

    for (int T = 0; T < nt; ++T) {
        const int bT = (T & 1) << 15;       // elem offset of buf(T)
        const int bNx = bT ^ 32768;         // buf(T+1)
        // ---- p0: compute (ks0, mf0-3); read A(mf4-7,ks0); stage T+1.a0,a2 ----
        RDA(afY, 1, 0, bT);
        if (T + 1 < nt) { STA(T + 1, 0, bNx); STA(T + 1, 2, bNx); }
        MIDSYNC;
        MFMA16(afX, bfA, 0);
        ENDSYNC;
        // ---- p1: compute (ks0, mf4-7); read A(mf0-3,ks1)+B(ks1); stage T+1.a1,a3 ----
        RDA(afX, 0, 1, bT);
        RDB(bfB, 1, bT);
        if (T + 1 < nt) { STA(T + 1, 1, bNx); STA(T + 1, 3, bNx); }
        MIDSYNC;
        MFMA16(afY, bfA, 4);
        ENDSYNC;
        // ---- p2: compute (ks1, mf0-3); read A(mf4-7,ks1); stage T+2.b0,b1 ----
        RDA(afY, 1, 1, bT);
        if (T + 2 < nt) { STB(T + 2, 0, bT); STB(T + 2, 1, bT); }
        MIDSYNC;
        MFMA16(afX, bfB, 0);
        ENDSYNC;
        // ---- p3: compute (ks1, mf4-7); read next tile A(mf0-3,ks0)+B(ks0); stage T+2.b2,b3 ----
        if (T + 1 < nt) {
            RDA(afX, 0, 0, bNx);
            RDB(bfA, 0, bNx);
        }
        if (T + 2 < nt) { STB(T + 2, 2, bT); STB(T + 2, 3, bT); }
        MIDSYNC;
        MFMA16(afY, bfB, 4);
        ENDSYNC;
    }

    // ---- epilogue: bias + relu + bf16 store ----
    const int rbase = by * BM + wm * 128 + (lane >> 4) * 4;
    const int cbase = bx * BN + wn * 64 + l15;
#pragma unroll
    for (int nf = 0; nf < 4; ++nf) {
        const int gc = cbase + nf * 16;
        const float bv = bias[gc];
#pragma unroll
        for (int mf = 0; mf < 8; ++mf) {
#pragma unroll
            for (int r = 0; r < 4; ++r) {
                int gr = rbase + mf * 16 + r;
                float h = acc[mf][nf][r] + bv;
                h = fmaxf(h, 0.0f);
                C[(size_t)gr * N + gc] = f2bf(h);
            }
        }
    }
#undef STA
#undef STB
#undef RDA
#undef RDB
#undef MFMA16
#undef MIDSYNC
#undef ENDSYNC
}

// ---------------- final matvec: out[m] = act[m,:] . col + b3[K-1] ----------------
__global__ __launch_bounds__(256) void k_matvec(const u16* __restrict__ act,
                                                const float* __restrict__ col,
                                                const float* __restrict__ b3,
                                                float* __restrict__ out, int K) {
    const int m = blockIdx.x, t = (int)threadIdx.x;
    const u16* row = act + (size_t)m * K;
    float acc = 0.f;
#pragma unroll
    for (int j = 0; j < 2; ++j) {
        int base = t * 16 + j * 8;
        short8 v = *(const short8*)(row + base);
#pragma unroll
        for (int u = 0; u < 8; ++u)
            acc += bf2f((u16)v[u]) * col[base + u];
    }
#pragma unroll
    for (int off = 32; off > 0; off >>= 1)
        acc += __shfl_down(acc, off);
    __shared__ float red[4];
    if ((t & 63) == 0) red[t >> 6] = acc;
    __syncthreads();
    if (t == 0) out[m] = red[0] + red[1] + red[2] + red[3] + b3[K - 1];
}

extern "C" void kernel_launch(void* const* d_in, const int* in_sizes, int n_in,
                              void* d_out, int out_size, void* d_ws, size_t ws_size,
                              hipStream_t stream) {
    const float* X  = (const float*)d_in[0];
    const float* W0 = (const float*)d_in[1];
    const float* b0 = (const float*)d_in[2];
    const float* W1 = (const float*)d_in[3];
    const float* b1 = (const float*)d_in[4];
    const float* W2 = (const float*)d_in[5];
    const float* b2 = (const float*)d_in[6];
    const float* W3 = (const float*)d_in[7];
    const float* b3 = (const float*)d_in[8];
    float* out = (float*)d_out;

    const int M = 8192, K0 = 1024, H = 4096;

    char* ws = (char*)d_ws;
    u16* Wt    = (u16*)(ws);                               // 33.5 MB (reused)
    u16* actA  = (u16*)(ws + 33554432);                    // 67.1 MB
    u16* actB  = (u16*)(ws + 33554432 + 67108864);         // 67.1 MB
    u16* Xb    = actB;                                     // alias: dead before actB written
    float* col = (float*)(ws + 33554432 + 2 * 67108864);   // 16 KB

    // 1. X -> bf16
    k_cvt<<<dim3((M * K0) / 1024), 256, 0, stream>>>(X, Xb, (long)M * K0);
    // 2. W0^T (no mask)
    k_transpose<<<dim3(H / 32, K0 / 32), dim3(32, 8), 0, stream>>>(W0, Wt, K0, H, 0);
    // 3. h0 = relu(X @ W0 + b0)
    k_gemm<<<dim3(H / BN, M / BM), 512, 0, stream>>>(Xb, Wt, b0, actA, M, H, K0, 0);
    // 4. W1^T masked
    k_transpose<<<dim3(H / 32, H / 32), dim3(32, 8), 0, stream>>>(W1, Wt, H, H, 1);
    // 5. h1 = relu(h0 @ W1eff + b1)   (variable-K per column tile, LPT order)
    k_gemm<<<dim3(H / BN, M / BM), 512, 0, stream>>>(actA, Wt, b1, actB, M, H, H, 1);
    // 6. W2^T masked
    k_transpose<<<dim3(H / 32, H / 32), dim3(32, 8), 0, stream>>>(W2, Wt, H, H, 1);
    // 7. h2 = relu(h1 @ W2eff + b2)
    k_gemm<<<dim3(H / BN, M / BM), 512, 0, stream>>>(actB, Wt, b2, actA, M, H, H, 1);
    // 8. W3 column 4095
    k_extract<<<dim3(H / 256), 256, 0, stream>>>(W3, col, H);
    // 9. out = h2 @ w3col + b3[4095]
    k_matvec<<<dim3(M), 256, 0, stream>>>(actA, col, b3, out, H);
}